// Round 2
// baseline (520.410 us; speedup 1.0000x reference)
//
#include <hip/hip_runtime.h>
#include <hip/hip_bf16.h>

// Problem constants (b=2, l=4, n=1024, dim=512, heads=8, dh=64, nsample=8)
// All d_in / d_out buffers are FLOAT32 (reference dtypes). Internal compute
// uses bf16 MFMA (allowed by the bf16-mode absmax threshold 0.105).
#define B_ 2
#define L_ 4
#define N_ 1024
#define DIM_ 512
#define INNER_ 512
#define HEADS_ 8
#define DH_ 64
#define NS_ 8
#define NFR_ (B_ * L_)            // 8 flat frames
#define ROWS_ (B_ * L_ * N_)      // 8192 point rows

typedef unsigned short u16;
typedef __attribute__((ext_vector_type(8))) short bf16x8;
typedef __attribute__((ext_vector_type(4))) float f32x4;

__device__ inline float bf2f(u16 u) {
    union { unsigned i; float f; } c; c.i = ((unsigned)u) << 16; return c.f;
}
__device__ inline u16 f2bf(float x) {
    __hip_bfloat16 h = __float2bfloat16(x);  // round-to-nearest-even
    return *reinterpret_cast<u16*>(&h);
}

// ---------------------------------------------------------------------------
// K0: transpose + bf16-cast w_qkv (512x1536 -> 1536x512) and w_out (512x512)
// ---------------------------------------------------------------------------
__global__ __launch_bounds__(256) void transpose_w(
    const float* __restrict__ wqkv, const float* __restrict__ wout,
    u16* __restrict__ wqkvT, u16* __restrict__ woutT)
{
    int i = blockIdx.x * 256 + threadIdx.x;
    const int T1 = DIM_ * 3 * INNER_;          // 786432
    if (i < T1) {
        int k = i / (3 * INNER_);
        int c = i - k * (3 * INNER_);
        wqkvT[c * DIM_ + k] = f2bf(wqkv[i]);
    } else {
        int i2 = i - T1;
        if (i2 < INNER_ * DIM_) {
            int k = i2 >> 9;                   // /512
            int c = i2 & 511;
            woutT[c * INNER_ + k] = f2bf(wout[i2]);
        }
    }
}

// ---------------------------------------------------------------------------
// K1: LayerNorm over channel dim (512) -> bf16 normf.  One block per row.
// ---------------------------------------------------------------------------
__global__ __launch_bounds__(256) void ln_kernel(
    const float* __restrict__ f, const float* __restrict__ g,
    const float* __restrict__ b, u16* __restrict__ o)
{
    int row = blockIdx.x;
    int t = threadIdx.x;
    const float* fr = f + (size_t)row * DIM_;
    float x0 = fr[t], x1 = fr[t + 256];

    __shared__ float red[4];
    float s = x0 + x1;
    #pragma unroll
    for (int off = 32; off; off >>= 1) s += __shfl_xor(s, off, 64);
    if ((t & 63) == 0) red[t >> 6] = s;
    __syncthreads();
    float mu = (red[0] + red[1] + red[2] + red[3]) * (1.0f / 512.0f);
    __syncthreads();

    float d0 = x0 - mu, d1 = x1 - mu;
    float q = d0 * d0 + d1 * d1;
    #pragma unroll
    for (int off = 32; off; off >>= 1) q += __shfl_xor(q, off, 64);
    if ((t & 63) == 0) red[t >> 6] = q;
    __syncthreads();
    float var = (red[0] + red[1] + red[2] + red[3]) * (1.0f / 512.0f);
    float inv = rsqrtf(var + 1e-5f);

    o[(size_t)row * DIM_ + t]       = f2bf(d0 * inv * g[t]       + b[t]);
    o[(size_t)row * DIM_ + t + 256] = f2bf(d1 * inv * g[t + 256] + b[t + 256]);
}

// ---------------------------------------------------------------------------
// K2/K5: MFMA bf16 GEMM, C[M,N] = A[M,K] @ Bt[N,K]^T.
// 128x128 block tile, BK=32, 256 threads (4 waves, each 64x64).
// mode 0: Cb16 = bf16(acc)                          (qkv, bf16 ws)
// mode 1: Cf32 = gelu(acc + bias) + resid           (final output, f32)
// ---------------------------------------------------------------------------
__global__ __launch_bounds__(256) void gemm_bt(
    const u16* __restrict__ A, const u16* __restrict__ Bt,
    u16* __restrict__ Cb16, float* __restrict__ Cf32,
    int M, int N, int K, int nb128, int mode,
    const float* __restrict__ bias, const float* __restrict__ resid)
{
    __shared__ u16 As[128 * 40];   // stride 40 bf16 = 80B (16B aligned)
    __shared__ u16 Bs[128 * 40];

    int bx = blockIdx.x % nb128;
    int by = blockIdx.x / nb128;
    int m0 = by * 128, n0 = bx * 128;
    int t = threadIdx.x;
    int wave = t >> 6, lane = t & 63;
    int lr = lane & 15, quad = lane >> 4;
    int wm = (wave >> 1) * 64, wn = (wave & 1) * 64;

    f32x4 acc[4][4];
    #pragma unroll
    for (int i = 0; i < 4; ++i)
        #pragma unroll
        for (int j = 0; j < 4; ++j)
            acc[i][j] = {0.f, 0.f, 0.f, 0.f};

    for (int k0 = 0; k0 < K; k0 += 32) {
        #pragma unroll
        for (int p = 0; p < 2; ++p) {
            int c = t + p * 256;           // 0..511
            int r = c >> 2;                // 0..127
            int kc = (c & 3) * 8;          // 0,8,16,24
            *(bf16x8*)&As[r * 40 + kc] = *(const bf16x8*)(A + (size_t)(m0 + r) * K + k0 + kc);
            *(bf16x8*)&Bs[r * 40 + kc] = *(const bf16x8*)(Bt + (size_t)(n0 + r) * K + k0 + kc);
        }
        __syncthreads();

        bf16x8 af[4], bfr[4];
        #pragma unroll
        for (int mb = 0; mb < 4; ++mb)
            af[mb] = *(const bf16x8*)&As[(wm + mb * 16 + lr) * 40 + quad * 8];
        #pragma unroll
        for (int nb = 0; nb < 4; ++nb)
            bfr[nb] = *(const bf16x8*)&Bs[(wn + nb * 16 + lr) * 40 + quad * 8];
        #pragma unroll
        for (int mb = 0; mb < 4; ++mb)
            #pragma unroll
            for (int nb = 0; nb < 4; ++nb)
                acc[mb][nb] = __builtin_amdgcn_mfma_f32_16x16x32_bf16(
                    af[mb], bfr[nb], acc[mb][nb], 0, 0, 0);
        __syncthreads();
    }

    #pragma unroll
    for (int mb = 0; mb < 4; ++mb) {
        #pragma unroll
        for (int nb = 0; nb < 4; ++nb) {
            int col = n0 + wn + nb * 16 + lr;
            #pragma unroll
            for (int r = 0; r < 4; ++r) {
                int row = m0 + wm + mb * 16 + quad * 4 + r;
                float x = acc[mb][nb][r];
                if (mode == 1) {
                    x += bias[col];
                    float gl = 0.5f * x * (1.0f + erff(x * 0.70710678118654752f));
                    Cf32[(size_t)row * N + col] = gl + resid[(size_t)row * N + col];
                } else {
                    Cb16[(size_t)row * N + col] = f2bf(x);
                }
            }
        }
    }
}

// ---------------------------------------------------------------------------
// K3: ball query. For (query-frame qi, batch bi, ref-frame jf, point n):
// first NS_ indices in ref frame (bi,jf) with d2 < R2 from query point
// (bi,qi,n); pad with first-found (or 0 if none). f32 xyz used directly so
// d2 matches the f32 reference bit-exactly (fp contract off, no FMA).
// ---------------------------------------------------------------------------
__global__ __launch_bounds__(256) void ballq_kernel(
    const float* __restrict__ xyz, int* __restrict__ idxt)
{
    #pragma clang fp contract(off)
    int blk = blockIdx.x;               // 128 blocks
    int nchunk = blk & 3;
    int combo = blk >> 2;               // qi*8 + bi*4 + jf
    int jf = combo & 3;
    int bi = (combo >> 2) & 1;
    int qi = combo >> 3;

    __shared__ float rx[N_], ry[N_], rz[N_];
    const float* ref = xyz + (size_t)((bi * L_ + jf) * N_) * 3;
    for (int p = threadIdx.x; p < N_; p += 256) {
        rx[p] = ref[p * 3 + 0];
        ry[p] = ref[p * 3 + 1];
        rz[p] = ref[p * 3 + 2];
    }
    __syncthreads();

    int n = nchunk * 256 + threadIdx.x;
    const float* qp = xyz + (size_t)((bi * L_ + qi) * N_ + n) * 3;
    float qx = qp[0], qy = qp[1], qz = qp[2];

    int found[NS_];
    int cnt = 0;
    for (int r = 0; r < N_; ++r) {
        if (cnt >= NS_) break;
        float dx = qx - rx[r];
        float dy = qy - ry[r];
        float dz = qz - rz[r];
        float d2 = dx * dx + dy * dy;
        d2 = d2 + dz * dz;
        if (d2 < 0.04f) { found[cnt] = r; ++cnt; }
    }
    int first = (cnt > 0) ? found[0] : 0;
    for (int s = cnt; s < NS_; ++s) found[s] = first;

    int* o = idxt + ((size_t)((qi * NFR_ + bi * L_ + jf) * N_) + n) * NS_;
    #pragma unroll
    for (int s = 0; s < NS_; ++s) o[s] = found[s];
}

// ---------------------------------------------------------------------------
// K4: attention. One block (512 thr = 8 waves = 8 heads) per (qi, bi, n).
// Wave = head h, lane = channel d (0..63). 32 neighbors = 4 frames x 8.
// ---------------------------------------------------------------------------
__global__ __launch_bounds__(512) void attn_kernel(
    const float* __restrict__ xyz, const u16* __restrict__ qkv,
    const int* __restrict__ idxt, const float* __restrict__ wsp,
    u16* __restrict__ fres)
{
    int blk = blockIdx.x;               // qi*2048 + bi*1024 + n
    int n = blk & 1023;
    int bc = blk >> 10;
    int bi = bc & 1;
    int qi = bc >> 1;
    int h = threadIdx.x >> 6;
    int lane = threadIdx.x & 63;

    int qrow = (bi * L_ + qi) * N_ + n;
    float qd = bf2f(qkv[(size_t)qrow * 1536 + h * 64 + lane]);
    float qx = xyz[(size_t)qrow * 3 + 0];
    float qy = xyz[(size_t)qrow * 3 + 1];
    float qz = xyz[(size_t)qrow * 3 + 2];

    float lg[32];
    int grow[32];
    #pragma unroll
    for (int j = 0; j < 32; ++j) {
        int jf = j >> 3, s = j & 7;
        int idx = idxt[((size_t)((qi * NFR_ + bi * L_ + jf) * N_) + n) * NS_ + s];
        int kr = (bi * L_ + jf) * N_ + idx;
        grow[j] = kr;
        float p = qd * bf2f(qkv[(size_t)kr * 1536 + 512 + h * 64 + lane]);
        #pragma unroll
        for (int off = 32; off; off >>= 1) p += __shfl_xor(p, off, 64);
        lg[j] = p * 0.125f;             // scale = dh^-0.5 = 1/8
    }

    float m = lg[0];
    #pragma unroll
    for (int j = 1; j < 32; ++j) m = fmaxf(m, lg[j]);
    float sum = 0.f;
    #pragma unroll
    for (int j = 0; j < 32; ++j) { lg[j] = expf(lg[j] - m); sum += lg[j]; }
    float inv = 1.0f / sum;

    float od = 0.f;
    float dax = 0.f, day = 0.f, daz = 0.f;
    #pragma unroll
    for (int j = 0; j < 32; ++j) {
        float a = lg[j] * inv;
        od += a * bf2f(qkv[(size_t)grow[j] * 1536 + 1024 + h * 64 + lane]);
        float gx = xyz[(size_t)grow[j] * 3 + 0] - qx;
        float gy = xyz[(size_t)grow[j] * 3 + 1] - qy;
        float gz = xyz[(size_t)grow[j] * 3 + 2] - qz;
        float tx = a * gx, ty = a * gy, tz = a * gz;
        if (j == 0) { dax = tx; day = ty; daz = tz; }
        else { dax = fmaxf(dax, tx); day = fmaxf(day, ty); daz = fmaxf(daz, tz); }
    }

    float sp = dax * wsp[lane] + day * wsp[64 + lane] + daz * wsp[128 + lane];
    fres[(size_t)qrow * INNER_ + h * 64 + lane] = f2bf(od + sp);
}

// ---------------------------------------------------------------------------
extern "C" void kernel_launch(void* const* d_in, const int* in_sizes, int n_in,
                              void* d_out, int out_size, void* d_ws, size_t ws_size,
                              hipStream_t stream) {
    const float* xyz   = (const float*)d_in[0];   // (2,4,1024,3)
    const float* feat  = (const float*)d_in[1];   // (2,4,1024,512)
    const float* gamma = (const float*)d_in[2];   // (512)
    const float* beta  = (const float*)d_in[3];   // (512)
    const float* wqkv  = (const float*)d_in[4];   // (512,1536)
    const float* wsp   = (const float*)d_in[5];   // (3,64)
    const float* wout  = (const float*)d_in[6];   // (512,512)
    const float* bout  = (const float*)d_in[7];   // (512)
    float* out = (float*)d_out;

    char* ws = (char*)d_ws;
    u16* normf = (u16*)ws;                 ws += (size_t)ROWS_ * DIM_ * 2;        // 8 MB
    u16* wqkvT = (u16*)ws;                 ws += (size_t)3 * INNER_ * DIM_ * 2;   // 1.5 MB
    u16* woutT = (u16*)ws;                 ws += (size_t)DIM_ * INNER_ * 2;       // 0.5 MB
    u16* qkv   = (u16*)ws;                 ws += (size_t)ROWS_ * 3 * INNER_ * 2;  // 24 MB
    int* idxt  = (int*)ws;                 ws += (size_t)L_ * NFR_ * N_ * NS_ * 4;// 1 MB
    u16* fres  = normf;   // alias: normf is dead after GEMM1 completes

    transpose_w<<<4096, 256, 0, stream>>>(wqkv, wout, wqkvT, woutT);
    ln_kernel<<<ROWS_, 256, 0, stream>>>(feat, gamma, beta, normf);
    // qkv = normf @ w_qkv : M=8192, N=1536, K=512
    gemm_bt<<<64 * 12, 256, 0, stream>>>(normf, wqkvT, qkv, nullptr,
                                         ROWS_, 3 * INNER_, DIM_, 12, 0, nullptr, nullptr);
    ballq_kernel<<<128, 256, 0, stream>>>(xyz, idxt);
    attn_kernel<<<L_ * B_ * N_, 512, 0, stream>>>(xyz, qkv, idxt, wsp, fres);
    // out = gelu(fres @ w_out + b_out) + feature : M=8192, N=512, K=512
    gemm_bt<<<64 * 4, 256, 0, stream>>>(fres, woutT, nullptr, out,
                                        ROWS_, DIM_, INNER_, 4, 1, bout, feat);
}

// Round 3
// 405.311 us; speedup vs baseline: 1.2840x; 1.2840x over previous
//
#include <hip/hip_runtime.h>
#include <hip/hip_bf16.h>

// Problem constants (b=2, l=4, n=1024, dim=512, heads=8, dh=64, nsample=8)
// All d_in / d_out buffers are FLOAT32 (reference dtypes). Internal compute
// uses bf16 MFMA (allowed by the bf16-mode absmax threshold 0.105).
#define B_ 2
#define L_ 4
#define N_ 1024
#define DIM_ 512
#define INNER_ 512
#define HEADS_ 8
#define DH_ 64
#define NS_ 8
#define NFR_ (B_ * L_)            // 8 flat frames
#define ROWS_ (B_ * L_ * N_)      // 8192 point rows

typedef unsigned short u16;
typedef __attribute__((ext_vector_type(8))) short bf16x8;
typedef __attribute__((ext_vector_type(4))) float f32x4;

__device__ inline float bf2f(u16 u) {
    union { unsigned i; float f; } c; c.i = ((unsigned)u) << 16; return c.f;
}
__device__ inline u16 f2bf(float x) {
    __hip_bfloat16 h = __float2bfloat16(x);  // round-to-nearest-even
    return *reinterpret_cast<u16*>(&h);
}

// ---------------------------------------------------------------------------
// K0: transpose + bf16-cast w_qkv (512x1536 -> 1536x512) and w_out (512x512)
// ---------------------------------------------------------------------------
__global__ __launch_bounds__(256) void transpose_w(
    const float* __restrict__ wqkv, const float* __restrict__ wout,
    u16* __restrict__ wqkvT, u16* __restrict__ woutT)
{
    int i = blockIdx.x * 256 + threadIdx.x;
    const int T1 = DIM_ * 3 * INNER_;          // 786432
    if (i < T1) {
        int k = i / (3 * INNER_);
        int c = i - k * (3 * INNER_);
        wqkvT[c * DIM_ + k] = f2bf(wqkv[i]);
    } else {
        int i2 = i - T1;
        if (i2 < INNER_ * DIM_) {
            int k = i2 >> 9;                   // /512
            int c = i2 & 511;
            woutT[c * INNER_ + k] = f2bf(wout[i2]);
        }
    }
}

// ---------------------------------------------------------------------------
// K1: LayerNorm over channel dim (512) -> bf16 normf.  One block per row.
// ---------------------------------------------------------------------------
__global__ __launch_bounds__(256) void ln_kernel(
    const float* __restrict__ f, const float* __restrict__ g,
    const float* __restrict__ b, u16* __restrict__ o)
{
    int row = blockIdx.x;
    int t = threadIdx.x;
    const float* fr = f + (size_t)row * DIM_;
    float x0 = fr[t], x1 = fr[t + 256];

    __shared__ float red[4];
    float s = x0 + x1;
    #pragma unroll
    for (int off = 32; off; off >>= 1) s += __shfl_xor(s, off, 64);
    if ((t & 63) == 0) red[t >> 6] = s;
    __syncthreads();
    float mu = (red[0] + red[1] + red[2] + red[3]) * (1.0f / 512.0f);
    __syncthreads();

    float d0 = x0 - mu, d1 = x1 - mu;
    float q = d0 * d0 + d1 * d1;
    #pragma unroll
    for (int off = 32; off; off >>= 1) q += __shfl_xor(q, off, 64);
    if ((t & 63) == 0) red[t >> 6] = q;
    __syncthreads();
    float var = (red[0] + red[1] + red[2] + red[3]) * (1.0f / 512.0f);
    float inv = rsqrtf(var + 1e-5f);

    o[(size_t)row * DIM_ + t]       = f2bf(d0 * inv * g[t]       + b[t]);
    o[(size_t)row * DIM_ + t + 256] = f2bf(d1 * inv * g[t + 256] + b[t + 256]);
}

// ---------------------------------------------------------------------------
// K2/K5: MFMA bf16 GEMM, C[M,N] = A[M,K] @ Bt[N,K]^T.
// 128x128 block tile, BK=32, 256 threads (4 waves, each 64x64).
// mode 0: Cb16 = bf16(acc)                          (qkv, bf16 ws)
// mode 1: Cf32 = gelu(acc + bias) + resid           (final output, f32)
// ---------------------------------------------------------------------------
__global__ __launch_bounds__(256) void gemm_bt(
    const u16* __restrict__ A, const u16* __restrict__ Bt,
    u16* __restrict__ Cb16, float* __restrict__ Cf32,
    int M, int N, int K, int nb128, int mode,
    const float* __restrict__ bias, const float* __restrict__ resid)
{
    __shared__ u16 As[128 * 40];   // stride 40 bf16 = 80B (16B aligned)
    __shared__ u16 Bs[128 * 40];

    int bx = blockIdx.x % nb128;
    int by = blockIdx.x / nb128;
    int m0 = by * 128, n0 = bx * 128;
    int t = threadIdx.x;
    int wave = t >> 6, lane = t & 63;
    int lr = lane & 15, quad = lane >> 4;
    int wm = (wave >> 1) * 64, wn = (wave & 1) * 64;

    f32x4 acc[4][4];
    #pragma unroll
    for (int i = 0; i < 4; ++i)
        #pragma unroll
        for (int j = 0; j < 4; ++j)
            acc[i][j] = {0.f, 0.f, 0.f, 0.f};

    for (int k0 = 0; k0 < K; k0 += 32) {
        #pragma unroll
        for (int p = 0; p < 2; ++p) {
            int c = t + p * 256;           // 0..511
            int r = c >> 2;                // 0..127
            int kc = (c & 3) * 8;          // 0,8,16,24
            *(bf16x8*)&As[r * 40 + kc] = *(const bf16x8*)(A + (size_t)(m0 + r) * K + k0 + kc);
            *(bf16x8*)&Bs[r * 40 + kc] = *(const bf16x8*)(Bt + (size_t)(n0 + r) * K + k0 + kc);
        }
        __syncthreads();

        bf16x8 af[4], bfr[4];
        #pragma unroll
        for (int mb = 0; mb < 4; ++mb)
            af[mb] = *(const bf16x8*)&As[(wm + mb * 16 + lr) * 40 + quad * 8];
        #pragma unroll
        for (int nb = 0; nb < 4; ++nb)
            bfr[nb] = *(const bf16x8*)&Bs[(wn + nb * 16 + lr) * 40 + quad * 8];
        #pragma unroll
        for (int mb = 0; mb < 4; ++mb)
            #pragma unroll
            for (int nb = 0; nb < 4; ++nb)
                acc[mb][nb] = __builtin_amdgcn_mfma_f32_16x16x32_bf16(
                    af[mb], bfr[nb], acc[mb][nb], 0, 0, 0);
        __syncthreads();
    }

    #pragma unroll
    for (int mb = 0; mb < 4; ++mb) {
        #pragma unroll
        for (int nb = 0; nb < 4; ++nb) {
            int col = n0 + wn + nb * 16 + lr;
            #pragma unroll
            for (int r = 0; r < 4; ++r) {
                int row = m0 + wm + mb * 16 + quad * 4 + r;
                float x = acc[mb][nb][r];
                if (mode == 1) {
                    x += bias[col];
                    float gl = 0.5f * x * (1.0f + erff(x * 0.70710678118654752f));
                    Cf32[(size_t)row * N + col] = gl + resid[(size_t)row * N + col];
                } else {
                    Cb16[(size_t)row * N + col] = f2bf(x);
                }
            }
        }
    }
}

// ---------------------------------------------------------------------------
// K3: ball query, wave-parallel. One wave per query; 64 lanes each test a
// contiguous 16-point chunk (lane order = index order), so prefix-sum of
// per-lane popcounts assigns the first-8-lowest-index output slots exactly
// like the sequential scan. Block = 4 waves = 4 queries sharing one
// LDS-staged ref frame. d2 math identical to reference (contract off).
// ---------------------------------------------------------------------------
__global__ __launch_bounds__(256) void ballq_kernel(
    const float* __restrict__ xyz, int* __restrict__ idxt)
{
    #pragma clang fp contract(off)
    int blk = blockIdx.x;               // 8192 blocks: combo*256 + qgroup
    int qgroup = blk & 255;
    int combo = blk >> 8;               // qi*8 + bi*4 + jf
    int jf = combo & 3;
    int bi = (combo >> 2) & 1;
    int qi = combo >> 3;

    __shared__ float rx[N_], ry[N_], rz[N_];
    const float* ref = xyz + (size_t)((bi * L_ + jf) * N_) * 3;
    for (int p = threadIdx.x; p < N_; p += 256) {
        rx[p] = ref[p * 3 + 0];
        ry[p] = ref[p * 3 + 1];
        rz[p] = ref[p * 3 + 2];
    }
    __syncthreads();

    int wave = threadIdx.x >> 6;
    int lane = threadIdx.x & 63;
    int n = qgroup * 4 + wave;

    const float* qp = xyz + (size_t)((bi * L_ + qi) * N_ + n) * 3;
    float qx = qp[0], qy = qp[1], qz = qp[2];

    int r0 = lane * 16;
    unsigned mask = 0;
    #pragma unroll
    for (int j = 0; j < 16; ++j) {
        int r = r0 + j;
        float dx = qx - rx[r];
        float dy = qy - ry[r];
        float dz = qz - rz[r];
        float d2 = dx * dx + dy * dy;
        d2 = d2 + dz * dz;
        if (d2 < 0.04f) mask |= (1u << j);
    }

    int cnt = __popc(mask);
    // inclusive prefix sum across 64 lanes
    int x = cnt;
    #pragma unroll
    for (int off = 1; off < 64; off <<= 1) {
        int y = __shfl_up(x, off, 64);
        if (lane >= off) x += y;
    }
    int pre = x - cnt;                       // exclusive prefix
    int total = __shfl(x, 63, 64);           // total in-radius count

    // lowest in-radius global index (for padding)
    int localFirst = mask ? (r0 + __builtin_ctz(mask)) : 0x7fffffff;
    int gfirst = localFirst;
    #pragma unroll
    for (int off = 32; off; off >>= 1) gfirst = min(gfirst, __shfl_xor(gfirst, off, 64));

    int* o = idxt + ((size_t)((qi * NFR_ + bi * L_ + jf) * N_) + n) * NS_;

    // emit this lane's in-radius indices at slots pre, pre+1, ... while < 8
    unsigned m = mask;
    int pos = pre;
    while (m && pos < NS_) {
        int j = __builtin_ctz(m);
        o[pos] = r0 + j;
        m &= m - 1;
        ++pos;
    }
    // padding: slots total..7 get first-found (or 0 if none)
    if (lane == 0) {
        int padv = (total > 0) ? gfirst : 0;
        for (int s = (total < NS_ ? total : NS_); s < NS_; ++s) o[s] = padv;
    }
}

// ---------------------------------------------------------------------------
// K4: attention. One block (512 thr = 8 waves = 8 heads) per (qi, bi, n).
// Wave = head h, lane = channel d (0..63). 32 neighbors = 4 frames x 8.
// ---------------------------------------------------------------------------
__global__ __launch_bounds__(512) void attn_kernel(
    const float* __restrict__ xyz, const u16* __restrict__ qkv,
    const int* __restrict__ idxt, const float* __restrict__ wsp,
    u16* __restrict__ fres)
{
    int blk = blockIdx.x;               // qi*2048 + bi*1024 + n
    int n = blk & 1023;
    int bc = blk >> 10;
    int bi = bc & 1;
    int qi = bc >> 1;
    int h = threadIdx.x >> 6;
    int lane = threadIdx.x & 63;

    int qrow = (bi * L_ + qi) * N_ + n;
    float qd = bf2f(qkv[(size_t)qrow * 1536 + h * 64 + lane]);
    float qx = xyz[(size_t)qrow * 3 + 0];
    float qy = xyz[(size_t)qrow * 3 + 1];
    float qz = xyz[(size_t)qrow * 3 + 2];

    float lg[32];
    int grow[32];
    #pragma unroll
    for (int j = 0; j < 32; ++j) {
        int jf = j >> 3, s = j & 7;
        int idx = idxt[((size_t)((qi * NFR_ + bi * L_ + jf) * N_) + n) * NS_ + s];
        int kr = (bi * L_ + jf) * N_ + idx;
        grow[j] = kr;
        float p = qd * bf2f(qkv[(size_t)kr * 1536 + 512 + h * 64 + lane]);
        #pragma unroll
        for (int off = 32; off; off >>= 1) p += __shfl_xor(p, off, 64);
        lg[j] = p * 0.125f;             // scale = dh^-0.5 = 1/8
    }

    float m = lg[0];
    #pragma unroll
    for (int j = 1; j < 32; ++j) m = fmaxf(m, lg[j]);
    float sum = 0.f;
    #pragma unroll
    for (int j = 0; j < 32; ++j) { lg[j] = expf(lg[j] - m); sum += lg[j]; }
    float inv = 1.0f / sum;

    float od = 0.f;
    float dax = 0.f, day = 0.f, daz = 0.f;
    #pragma unroll
    for (int j = 0; j < 32; ++j) {
        float a = lg[j] * inv;
        od += a * bf2f(qkv[(size_t)grow[j] * 1536 + 1024 + h * 64 + lane]);
        float gx = xyz[(size_t)grow[j] * 3 + 0] - qx;
        float gy = xyz[(size_t)grow[j] * 3 + 1] - qy;
        float gz = xyz[(size_t)grow[j] * 3 + 2] - qz;
        float tx = a * gx, ty = a * gy, tz = a * gz;
        if (j == 0) { dax = tx; day = ty; daz = tz; }
        else { dax = fmaxf(dax, tx); day = fmaxf(day, ty); daz = fmaxf(daz, tz); }
    }

    float sp = dax * wsp[lane] + day * wsp[64 + lane] + daz * wsp[128 + lane];
    fres[(size_t)qrow * INNER_ + h * 64 + lane] = f2bf(od + sp);
}

// ---------------------------------------------------------------------------
extern "C" void kernel_launch(void* const* d_in, const int* in_sizes, int n_in,
                              void* d_out, int out_size, void* d_ws, size_t ws_size,
                              hipStream_t stream) {
    const float* xyz   = (const float*)d_in[0];   // (2,4,1024,3)
    const float* feat  = (const float*)d_in[1];   // (2,4,1024,512)
    const float* gamma = (const float*)d_in[2];   // (512)
    const float* beta  = (const float*)d_in[3];   // (512)
    const float* wqkv  = (const float*)d_in[4];   // (512,1536)
    const float* wsp   = (const float*)d_in[5];   // (3,64)
    const float* wout  = (const float*)d_in[6];   // (512,512)
    const float* bout  = (const float*)d_in[7];   // (512)
    float* out = (float*)d_out;

    char* ws = (char*)d_ws;
    u16* normf = (u16*)ws;                 ws += (size_t)ROWS_ * DIM_ * 2;        // 8 MB
    u16* wqkvT = (u16*)ws;                 ws += (size_t)3 * INNER_ * DIM_ * 2;   // 1.5 MB
    u16* woutT = (u16*)ws;                 ws += (size_t)DIM_ * INNER_ * 2;       // 0.5 MB
    u16* qkv   = (u16*)ws;                 ws += (size_t)ROWS_ * 3 * INNER_ * 2;  // 24 MB
    int* idxt  = (int*)ws;                 ws += (size_t)L_ * NFR_ * N_ * NS_ * 4;// 1 MB
    u16* fres  = normf;   // alias: normf is dead after GEMM1 completes

    transpose_w<<<4096, 256, 0, stream>>>(wqkv, wout, wqkvT, woutT);
    ln_kernel<<<ROWS_, 256, 0, stream>>>(feat, gamma, beta, normf);
    // qkv = normf @ w_qkv : M=8192, N=1536, K=512
    gemm_bt<<<64 * 12, 256, 0, stream>>>(normf, wqkvT, qkv, nullptr,
                                         ROWS_, 3 * INNER_, DIM_, 12, 0, nullptr, nullptr);
    ballq_kernel<<<32 * 256, 256, 0, stream>>>(xyz, idxt);
    attn_kernel<<<L_ * B_ * N_, 512, 0, stream>>>(xyz, qkv, idxt, wsp, fres);
    // out = gelu(fres @ w_out + b_out) + feature : M=8192, N=512, K=512
    gemm_bt<<<64 * 4, 256, 0, stream>>>(fres, woutT, nullptr, out,
                                        ROWS_, DIM_, INNER_, 4, 1, bout, feat);
}

// Round 4
// 317.225 us; speedup vs baseline: 1.6405x; 1.2777x over previous
//
#include <hip/hip_runtime.h>
#include <hip/hip_bf16.h>

// Problem constants (b=2, l=4, n=1024, dim=512, heads=8, dh=64, nsample=8)
// All d_in / d_out buffers are FLOAT32 (reference dtypes). Internal compute
// uses bf16 MFMA (allowed by the bf16-mode absmax threshold 0.105).
#define B_ 2
#define L_ 4
#define N_ 1024
#define DIM_ 512
#define INNER_ 512
#define HEADS_ 8
#define DH_ 64
#define NS_ 8
#define NFR_ (B_ * L_)            // 8 flat frames
#define ROWS_ (B_ * L_ * N_)      // 8192 point rows

typedef unsigned short u16;
typedef __attribute__((ext_vector_type(8))) short bf16x8;
typedef __attribute__((ext_vector_type(4))) float f32x4;

__device__ inline float bf2f(u16 u) {
    union { unsigned i; float f; } c; c.i = ((unsigned)u) << 16; return c.f;
}
__device__ inline float bflo(unsigned v) {   // low bf16 of dword -> f32
    union { unsigned i; float f; } c; c.i = v << 16; return c.f;
}
__device__ inline float bfhi(unsigned v) {   // high bf16 of dword -> f32
    union { unsigned i; float f; } c; c.i = v & 0xffff0000u; return c.f;
}
__device__ inline u16 f2bf(float x) {
    __hip_bfloat16 h = __float2bfloat16(x);  // round-to-nearest-even
    return *reinterpret_cast<u16*>(&h);
}

// ---------------------------------------------------------------------------
// K0: transpose + bf16-cast w_qkv (512x1536 -> 1536x512) and w_out (512x512)
// ---------------------------------------------------------------------------
__global__ __launch_bounds__(256) void transpose_w(
    const float* __restrict__ wqkv, const float* __restrict__ wout,
    u16* __restrict__ wqkvT, u16* __restrict__ woutT)
{
    int i = blockIdx.x * 256 + threadIdx.x;
    const int T1 = DIM_ * 3 * INNER_;          // 786432
    if (i < T1) {
        int k = i / (3 * INNER_);
        int c = i - k * (3 * INNER_);
        wqkvT[c * DIM_ + k] = f2bf(wqkv[i]);
    } else {
        int i2 = i - T1;
        if (i2 < INNER_ * DIM_) {
            int k = i2 >> 9;                   // /512
            int c = i2 & 511;
            woutT[c * INNER_ + k] = f2bf(wout[i2]);
        }
    }
}

// ---------------------------------------------------------------------------
// K1: LayerNorm over channel dim (512) -> bf16 normf.  One block per row.
// ---------------------------------------------------------------------------
__global__ __launch_bounds__(256) void ln_kernel(
    const float* __restrict__ f, const float* __restrict__ g,
    const float* __restrict__ b, u16* __restrict__ o)
{
    int row = blockIdx.x;
    int t = threadIdx.x;
    const float* fr = f + (size_t)row * DIM_;
    float x0 = fr[t], x1 = fr[t + 256];

    __shared__ float red[4];
    float s = x0 + x1;
    #pragma unroll
    for (int off = 32; off; off >>= 1) s += __shfl_xor(s, off, 64);
    if ((t & 63) == 0) red[t >> 6] = s;
    __syncthreads();
    float mu = (red[0] + red[1] + red[2] + red[3]) * (1.0f / 512.0f);
    __syncthreads();

    float d0 = x0 - mu, d1 = x1 - mu;
    float q = d0 * d0 + d1 * d1;
    #pragma unroll
    for (int off = 32; off; off >>= 1) q += __shfl_xor(q, off, 64);
    if ((t & 63) == 0) red[t >> 6] = q;
    __syncthreads();
    float var = (red[0] + red[1] + red[2] + red[3]) * (1.0f / 512.0f);
    float inv = rsqrtf(var + 1e-5f);

    o[(size_t)row * DIM_ + t]       = f2bf(d0 * inv * g[t]       + b[t]);
    o[(size_t)row * DIM_ + t + 256] = f2bf(d1 * inv * g[t + 256] + b[t + 256]);
}

// ---------------------------------------------------------------------------
// K2/K5: MFMA bf16 GEMM, C[M,N] = A[M,K] @ Bt[N,K]^T.
// 128x128 block tile, BK=32, 256 threads (4 waves, each 64x64).
// mode 0: Cb16 = bf16(acc)                          (qkv, bf16 ws)
// mode 1: Cf32 = gelu(acc + bias) + resid           (final output, f32)
// ---------------------------------------------------------------------------
__global__ __launch_bounds__(256) void gemm_bt(
    const u16* __restrict__ A, const u16* __restrict__ Bt,
    u16* __restrict__ Cb16, float* __restrict__ Cf32,
    int M, int N, int K, int nb128, int mode,
    const float* __restrict__ bias, const float* __restrict__ resid)
{
    __shared__ u16 As[128 * 40];   // stride 40 bf16 = 80B (16B aligned)
    __shared__ u16 Bs[128 * 40];

    int bx = blockIdx.x % nb128;
    int by = blockIdx.x / nb128;
    int m0 = by * 128, n0 = bx * 128;
    int t = threadIdx.x;
    int wave = t >> 6, lane = t & 63;
    int lr = lane & 15, quad = lane >> 4;
    int wm = (wave >> 1) * 64, wn = (wave & 1) * 64;

    f32x4 acc[4][4];
    #pragma unroll
    for (int i = 0; i < 4; ++i)
        #pragma unroll
        for (int j = 0; j < 4; ++j)
            acc[i][j] = {0.f, 0.f, 0.f, 0.f};

    for (int k0 = 0; k0 < K; k0 += 32) {
        #pragma unroll
        for (int p = 0; p < 2; ++p) {
            int c = t + p * 256;           // 0..511
            int r = c >> 2;                // 0..127
            int kc = (c & 3) * 8;          // 0,8,16,24
            *(bf16x8*)&As[r * 40 + kc] = *(const bf16x8*)(A + (size_t)(m0 + r) * K + k0 + kc);
            *(bf16x8*)&Bs[r * 40 + kc] = *(const bf16x8*)(Bt + (size_t)(n0 + r) * K + k0 + kc);
        }
        __syncthreads();

        bf16x8 af[4], bfr[4];
        #pragma unroll
        for (int mb = 0; mb < 4; ++mb)
            af[mb] = *(const bf16x8*)&As[(wm + mb * 16 + lr) * 40 + quad * 8];
        #pragma unroll
        for (int nb = 0; nb < 4; ++nb)
            bfr[nb] = *(const bf16x8*)&Bs[(wn + nb * 16 + lr) * 40 + quad * 8];
        #pragma unroll
        for (int mb = 0; mb < 4; ++mb)
            #pragma unroll
            for (int nb = 0; nb < 4; ++nb)
                acc[mb][nb] = __builtin_amdgcn_mfma_f32_16x16x32_bf16(
                    af[mb], bfr[nb], acc[mb][nb], 0, 0, 0);
        __syncthreads();
    }

    #pragma unroll
    for (int mb = 0; mb < 4; ++mb) {
        #pragma unroll
        for (int nb = 0; nb < 4; ++nb) {
            int col = n0 + wn + nb * 16 + lr;
            #pragma unroll
            for (int r = 0; r < 4; ++r) {
                int row = m0 + wm + mb * 16 + quad * 4 + r;
                float x = acc[mb][nb][r];
                if (mode == 1) {
                    x += bias[col];
                    float gl = 0.5f * x * (1.0f + erff(x * 0.70710678118654752f));
                    Cf32[(size_t)row * N + col] = gl + resid[(size_t)row * N + col];
                } else {
                    Cb16[(size_t)row * N + col] = f2bf(x);
                }
            }
        }
    }
}

// ---------------------------------------------------------------------------
// K3: ball query, wave-parallel. One wave per query; 64 lanes each test a
// contiguous 16-point chunk (lane order = index order), so prefix-sum of
// per-lane popcounts assigns the first-8-lowest-index output slots exactly
// like the sequential scan. Block = 4 waves = 4 queries sharing one
// LDS-staged ref frame. d2 math identical to reference (contract off).
// idxt layout: [(qi*2+bi)*1024+n][jf*8+s]  (32 consecutive ints per query)
// ---------------------------------------------------------------------------
__global__ __launch_bounds__(256) void ballq_kernel(
    const float* __restrict__ xyz, int* __restrict__ idxt)
{
    #pragma clang fp contract(off)
    int blk = blockIdx.x;               // 8192 blocks: combo*256 + qgroup
    int qgroup = blk & 255;
    int combo = blk >> 8;               // qi*8 + bi*4 + jf
    int jf = combo & 3;
    int bi = (combo >> 2) & 1;
    int qi = combo >> 3;

    __shared__ float rx[N_], ry[N_], rz[N_];
    const float* ref = xyz + (size_t)((bi * L_ + jf) * N_) * 3;
    for (int p = threadIdx.x; p < N_; p += 256) {
        rx[p] = ref[p * 3 + 0];
        ry[p] = ref[p * 3 + 1];
        rz[p] = ref[p * 3 + 2];
    }
    __syncthreads();

    int wave = threadIdx.x >> 6;
    int lane = threadIdx.x & 63;
    int n = qgroup * 4 + wave;

    const float* qp = xyz + (size_t)((bi * L_ + qi) * N_ + n) * 3;
    float qx = qp[0], qy = qp[1], qz = qp[2];

    int r0 = lane * 16;
    unsigned mask = 0;
    #pragma unroll
    for (int j = 0; j < 16; ++j) {
        int r = r0 + j;
        float dx = qx - rx[r];
        float dy = qy - ry[r];
        float dz = qz - rz[r];
        float d2 = dx * dx + dy * dy;
        d2 = d2 + dz * dz;
        if (d2 < 0.04f) mask |= (1u << j);
    }

    int cnt = __popc(mask);
    int x = cnt;
    #pragma unroll
    for (int off = 1; off < 64; off <<= 1) {
        int y = __shfl_up(x, off, 64);
        if (lane >= off) x += y;
    }
    int pre = x - cnt;                       // exclusive prefix
    int total = __shfl(x, 63, 64);           // total in-radius count

    int localFirst = mask ? (r0 + __builtin_ctz(mask)) : 0x7fffffff;
    int gfirst = localFirst;
    #pragma unroll
    for (int off = 32; off; off >>= 1) gfirst = min(gfirst, __shfl_xor(gfirst, off, 64));

    int* o = idxt + ((size_t)((qi * B_ + bi) * N_ + n)) * 32 + jf * NS_;

    unsigned m = mask;
    int pos = pre;
    while (m && pos < NS_) {
        int j = __builtin_ctz(m);
        o[pos] = r0 + j;
        m &= m - 1;
        ++pos;
    }
    if (lane == 0) {
        int padv = (total > 0) ? gfirst : 0;
        for (int s = (total < NS_ ? total : NS_); s < NS_; ++s) o[s] = padv;
    }
}

// ---------------------------------------------------------------------------
// K4: attention, relayout. One block (256 thr = 4 waves) per query point.
// Wave w covers heads 2w, 2w+1.
// Phase A (lane = (head-half hh, neighbor j)): in-lane 64-dim QK dot,
//   32-lane-group softmax + attn*disp max.  No per-j wave reductions.
// Phase C (lane = (hh, dim-pair)): PV with dword V loads + spatial proj.
// ---------------------------------------------------------------------------
__global__ __launch_bounds__(256) void attn_kernel(
    const float* __restrict__ xyz, const u16* __restrict__ qkv,
    const int* __restrict__ idxt, const float* __restrict__ wsp,
    u16* __restrict__ fres)
{
    int n = blockIdx.x & 1023;
    int bc = blockIdx.x >> 10;
    int bi = bc & 1;
    int qi = bc >> 1;
    int wave = threadIdx.x >> 6;
    int lane = threadIdx.x & 63;
    int hh = lane >> 5;
    int j = lane & 31;
    int h = wave * 2 + hh;
    int jf = j >> 3;

    int qrow = (bi * L_ + qi) * N_ + n;                  // xyz/qkv row
    int qq = (qi * B_ + bi) * N_ + n;                    // idxt row

    __shared__ float a_s[HEADS_][32];
    __shared__ int grow_s[32];
    __shared__ float da_s[HEADS_][3];

    // --- Phase A: logits ---
    int idx = idxt[(size_t)qq * 32 + j];                 // coalesced 128B / group
    int kr = (bi * L_ + jf) * N_ + idx;

    const u16* kp = qkv + (size_t)kr * 1536 + 512 + h * 64;
    const u16* qp = qkv + (size_t)qrow * 1536 + h * 64;

    bf16x8 kvv[8], qvv[8];
    #pragma unroll
    for (int c = 0; c < 8; ++c) {
        kvv[c] = *(const bf16x8*)(kp + c * 8);
        qvv[c] = *(const bf16x8*)(qp + c * 8);
    }
    float acc = 0.f;
    #pragma unroll
    for (int c = 0; c < 8; ++c)
        #pragma unroll
        for (int e = 0; e < 8; ++e)
            acc += bf2f((u16)kvv[c][e]) * bf2f((u16)qvv[c][e]);

    float lg = acc * 0.125f;                             // scale = dh^-0.5

    // --- softmax over 32-lane group (xor offsets < 32 stay in group) ---
    float mx = lg;
    #pragma unroll
    for (int off = 16; off; off >>= 1) mx = fmaxf(mx, __shfl_xor(mx, off, 64));
    float e = expf(lg - mx);
    float sum = e;
    #pragma unroll
    for (int off = 16; off; off >>= 1) sum += __shfl_xor(sum, off, 64);
    float a = e / sum;
    a_s[h][j] = a;
    if (wave == 0 && hh == 0) grow_s[j] = kr;

    // --- attn * disp max (per head, over 32 neighbors) ---
    float qx = xyz[(size_t)qrow * 3 + 0];
    float qy = xyz[(size_t)qrow * 3 + 1];
    float qz = xyz[(size_t)qrow * 3 + 2];
    float tx = a * (xyz[(size_t)kr * 3 + 0] - qx);
    float ty = a * (xyz[(size_t)kr * 3 + 1] - qy);
    float tz = a * (xyz[(size_t)kr * 3 + 2] - qz);
    #pragma unroll
    for (int off = 16; off; off >>= 1) {
        tx = fmaxf(tx, __shfl_xor(tx, off, 64));
        ty = fmaxf(ty, __shfl_xor(ty, off, 64));
        tz = fmaxf(tz, __shfl_xor(tz, off, 64));
    }
    if (j == 0) { da_s[h][0] = tx; da_s[h][1] = ty; da_s[h][2] = tz; }

    __syncthreads();

    // --- Phase C: PV + spatial projection.  lane -> (hh, dim pair) ---
    int dd = (lane & 31) * 2;                            // dims dd, dd+1
    const u16* vbase = qkv + 1024 + h * 64 + dd;
    float o0 = 0.f, o1 = 0.f;
    #pragma unroll
    for (int t = 0; t < 32; ++t) {
        int krt = grow_s[t];
        float at = a_s[h][t];
        unsigned vv = *(const unsigned*)(vbase + (size_t)krt * 1536);
        o0 += at * bflo(vv);
        o1 += at * bfhi(vv);
    }
    float dax = da_s[h][0], day = da_s[h][1], daz = da_s[h][2];
    float sp0 = dax * wsp[dd]     + day * wsp[64 + dd]     + daz * wsp[128 + dd];
    float sp1 = dax * wsp[dd + 1] + day * wsp[64 + dd + 1] + daz * wsp[128 + dd + 1];

    u16* op = fres + (size_t)qrow * INNER_ + h * 64 + dd;
    unsigned outw = (unsigned)f2bf(o0 + sp0) | ((unsigned)f2bf(o1 + sp1) << 16);
    *(unsigned*)op = outw;
}

// ---------------------------------------------------------------------------
extern "C" void kernel_launch(void* const* d_in, const int* in_sizes, int n_in,
                              void* d_out, int out_size, void* d_ws, size_t ws_size,
                              hipStream_t stream) {
    const float* xyz   = (const float*)d_in[0];   // (2,4,1024,3)
    const float* feat  = (const float*)d_in[1];   // (2,4,1024,512)
    const float* gamma = (const float*)d_in[2];   // (512)
    const float* beta  = (const float*)d_in[3];   // (512)
    const float* wqkv  = (const float*)d_in[4];   // (512,1536)
    const float* wsp   = (const float*)d_in[5];   // (3,64)
    const float* wout  = (const float*)d_in[6];   // (512,512)
    const float* bout  = (const float*)d_in[7];   // (512)
    float* out = (float*)d_out;

    char* ws = (char*)d_ws;
    u16* normf = (u16*)ws;                 ws += (size_t)ROWS_ * DIM_ * 2;        // 8 MB
    u16* wqkvT = (u16*)ws;                 ws += (size_t)3 * INNER_ * DIM_ * 2;   // 1.5 MB
    u16* woutT = (u16*)ws;                 ws += (size_t)DIM_ * INNER_ * 2;       // 0.5 MB
    u16* qkv   = (u16*)ws;                 ws += (size_t)ROWS_ * 3 * INNER_ * 2;  // 24 MB
    int* idxt  = (int*)ws;                 ws += (size_t)L_ * NFR_ * N_ * NS_ * 4;// 1 MB
    u16* fres  = normf;   // alias: normf is dead after GEMM1 completes

    transpose_w<<<4096, 256, 0, stream>>>(wqkv, wout, wqkvT, woutT);
    ln_kernel<<<ROWS_, 256, 0, stream>>>(feat, gamma, beta, normf);
    // qkv = normf @ w_qkv : M=8192, N=1536, K=512
    gemm_bt<<<64 * 12, 256, 0, stream>>>(normf, wqkvT, qkv, nullptr,
                                         ROWS_, 3 * INNER_, DIM_, 12, 0, nullptr, nullptr);
    ballq_kernel<<<32 * 256, 256, 0, stream>>>(xyz, idxt);
    attn_kernel<<<L_ * B_ * N_, 256, 0, stream>>>(xyz, qkv, idxt, wsp, fres);
    // out = gelu(fres @ w_out + b_out) + feature : M=8192, N=512, K=512
    gemm_bt<<<64 * 4, 256, 0, stream>>>(fres, woutT, nullptr, out,
                                        ROWS_, DIM_, INNER_, 4, 1, bout, feat);
}

// Round 5
// 245.811 us; speedup vs baseline: 2.1171x; 1.2905x over previous
//
#include <hip/hip_runtime.h>
#include <hip/hip_bf16.h>

// Problem constants (b=2, l=4, n=1024, dim=512, heads=8, dh=64, nsample=8)
// All d_in / d_out buffers are FLOAT32 (reference dtypes). Internal compute
// uses bf16 MFMA (allowed by the bf16-mode absmax threshold 0.105).
#define B_ 2
#define L_ 4
#define N_ 1024
#define DIM_ 512
#define INNER_ 512
#define HEADS_ 8
#define DH_ 64
#define NS_ 8
#define NFR_ (B_ * L_)            // 8 flat frames
#define ROWS_ (B_ * L_ * N_)      // 8192 point rows

typedef unsigned short u16;
typedef __attribute__((ext_vector_type(8))) short bf16x8;
typedef __attribute__((ext_vector_type(4))) float f32x4;

__device__ inline float bf2f(u16 u) {
    union { unsigned i; float f; } c; c.i = ((unsigned)u) << 16; return c.f;
}
__device__ inline float bflo(unsigned v) {   // low bf16 of dword -> f32
    union { unsigned i; float f; } c; c.i = v << 16; return c.f;
}
__device__ inline float bfhi(unsigned v) {   // high bf16 of dword -> f32
    union { unsigned i; float f; } c; c.i = v & 0xffff0000u; return c.f;
}
__device__ inline u16 f2bf(float x) {
    __hip_bfloat16 h = __float2bfloat16(x);  // round-to-nearest-even
    return *reinterpret_cast<u16*>(&h);
}

// ---------------------------------------------------------------------------
// K0: transpose + bf16-cast w_qkv (512x1536 -> 1536x512) and w_out (512x512)
// ---------------------------------------------------------------------------
__global__ __launch_bounds__(256) void transpose_w(
    const float* __restrict__ wqkv, const float* __restrict__ wout,
    u16* __restrict__ wqkvT, u16* __restrict__ woutT)
{
    int i = blockIdx.x * 256 + threadIdx.x;
    const int T1 = DIM_ * 3 * INNER_;          // 786432
    if (i < T1) {
        int k = i / (3 * INNER_);
        int c = i - k * (3 * INNER_);
        wqkvT[c * DIM_ + k] = f2bf(wqkv[i]);
    } else {
        int i2 = i - T1;
        if (i2 < INNER_ * DIM_) {
            int k = i2 >> 9;                   // /512
            int c = i2 & 511;
            woutT[c * INNER_ + k] = f2bf(wout[i2]);
        }
    }
}

// ---------------------------------------------------------------------------
// K1: LayerNorm over channel dim (512) -> bf16 normf.  One block per row.
// ---------------------------------------------------------------------------
__global__ __launch_bounds__(256) void ln_kernel(
    const float* __restrict__ f, const float* __restrict__ g,
    const float* __restrict__ b, u16* __restrict__ o)
{
    int row = blockIdx.x;
    int t = threadIdx.x;
    const float* fr = f + (size_t)row * DIM_;
    float x0 = fr[t], x1 = fr[t + 256];

    __shared__ float red[4];
    float s = x0 + x1;
    #pragma unroll
    for (int off = 32; off; off >>= 1) s += __shfl_xor(s, off, 64);
    if ((t & 63) == 0) red[t >> 6] = s;
    __syncthreads();
    float mu = (red[0] + red[1] + red[2] + red[3]) * (1.0f / 512.0f);
    __syncthreads();

    float d0 = x0 - mu, d1 = x1 - mu;
    float q = d0 * d0 + d1 * d1;
    #pragma unroll
    for (int off = 32; off; off >>= 1) q += __shfl_xor(q, off, 64);
    if ((t & 63) == 0) red[t >> 6] = q;
    __syncthreads();
    float var = (red[0] + red[1] + red[2] + red[3]) * (1.0f / 512.0f);
    float inv = rsqrtf(var + 1e-5f);

    o[(size_t)row * DIM_ + t]       = f2bf(d0 * inv * g[t]       + b[t]);
    o[(size_t)row * DIM_ + t + 256] = f2bf(d1 * inv * g[t + 256] + b[t + 256]);
}

// ---------------------------------------------------------------------------
// K2/K5: MFMA bf16 GEMM, C[M,N] = A[M,K] @ Bt[N,K]^T.
// 128x128 block tile, BK=32, 256 threads (4 waves, each 64x64).
// mode 0: Cb16 = bf16(acc)                          (qkv, bf16 ws)
// mode 1: Cf32 = gelu(acc + bias) + resid           (final output, f32)
// ---------------------------------------------------------------------------
__global__ __launch_bounds__(256) void gemm_bt(
    const u16* __restrict__ A, const u16* __restrict__ Bt,
    u16* __restrict__ Cb16, float* __restrict__ Cf32,
    int M, int N, int K, int nb128, int mode,
    const float* __restrict__ bias, const float* __restrict__ resid)
{
    __shared__ u16 As[128 * 40];   // stride 40 bf16 = 80B (16B aligned)
    __shared__ u16 Bs[128 * 40];

    int bx = blockIdx.x % nb128;
    int by = blockIdx.x / nb128;
    int m0 = by * 128, n0 = bx * 128;
    int t = threadIdx.x;
    int wave = t >> 6, lane = t & 63;
    int lr = lane & 15, quad = lane >> 4;
    int wm = (wave >> 1) * 64, wn = (wave & 1) * 64;

    f32x4 acc[4][4];
    #pragma unroll
    for (int i = 0; i < 4; ++i)
        #pragma unroll
        for (int j = 0; j < 4; ++j)
            acc[i][j] = {0.f, 0.f, 0.f, 0.f};

    for (int k0 = 0; k0 < K; k0 += 32) {
        #pragma unroll
        for (int p = 0; p < 2; ++p) {
            int c = t + p * 256;           // 0..511
            int r = c >> 2;                // 0..127
            int kc = (c & 3) * 8;          // 0,8,16,24
            *(bf16x8*)&As[r * 40 + kc] = *(const bf16x8*)(A + (size_t)(m0 + r) * K + k0 + kc);
            *(bf16x8*)&Bs[r * 40 + kc] = *(const bf16x8*)(Bt + (size_t)(n0 + r) * K + k0 + kc);
        }
        __syncthreads();

        bf16x8 af[4], bfr[4];
        #pragma unroll
        for (int mb = 0; mb < 4; ++mb)
            af[mb] = *(const bf16x8*)&As[(wm + mb * 16 + lr) * 40 + quad * 8];
        #pragma unroll
        for (int nb = 0; nb < 4; ++nb)
            bfr[nb] = *(const bf16x8*)&Bs[(wn + nb * 16 + lr) * 40 + quad * 8];
        #pragma unroll
        for (int mb = 0; mb < 4; ++mb)
            #pragma unroll
            for (int nb = 0; nb < 4; ++nb)
                acc[mb][nb] = __builtin_amdgcn_mfma_f32_16x16x32_bf16(
                    af[mb], bfr[nb], acc[mb][nb], 0, 0, 0);
        __syncthreads();
    }

    #pragma unroll
    for (int mb = 0; mb < 4; ++mb) {
        #pragma unroll
        for (int nb = 0; nb < 4; ++nb) {
            int col = n0 + wn + nb * 16 + lr;
            #pragma unroll
            for (int r = 0; r < 4; ++r) {
                int row = m0 + wm + mb * 16 + quad * 4 + r;
                float x = acc[mb][nb][r];
                if (mode == 1) {
                    x += bias[col];
                    float gl = 0.5f * x * (1.0f + erff(x * 0.70710678118654752f));
                    Cf32[(size_t)row * N + col] = gl + resid[(size_t)row * N + col];
                } else {
                    Cb16[(size_t)row * N + col] = f2bf(x);
                }
            }
        }
    }
}

// ---------------------------------------------------------------------------
// K3: ball query, wave-parallel. One wave per query; 64 lanes each test a
// contiguous 16-point chunk (lane order = index order), so prefix-sum of
// per-lane popcounts assigns the first-8-lowest-index output slots exactly
// like the sequential scan. Block = 4 waves = 4 queries sharing one
// LDS-staged ref frame.
// LDS pad: R(r)=r+(r>>4) -> read addr = lane*17+j; 17 coprime 32 => every
// bank hit by exactly 2 lanes (free). Fixes the 32-way conflict (4.7e7
// conflict cycles = 77us) seen with the unpadded lane*16 layout.
// d2 math identical to reference (contract off).
// idxt layout: [(qi*2+bi)*1024+n][jf*8+s]  (32 consecutive ints per query)
// ---------------------------------------------------------------------------
#define RPAD_(r) ((r) + ((r) >> 4))

__global__ __launch_bounds__(256) void ballq_kernel(
    const float* __restrict__ xyz, int* __restrict__ idxt)
{
    #pragma clang fp contract(off)
    int blk = blockIdx.x;               // 8192 blocks: combo*256 + qgroup
    int qgroup = blk & 255;
    int combo = blk >> 8;               // qi*8 + bi*4 + jf
    int jf = combo & 3;
    int bi = (combo >> 2) & 1;
    int qi = combo >> 3;

    __shared__ float rx[N_ + (N_ >> 4)], ry[N_ + (N_ >> 4)], rz[N_ + (N_ >> 4)];
    const float* ref = xyz + (size_t)((bi * L_ + jf) * N_) * 3;
    for (int p = threadIdx.x; p < N_; p += 256) {
        rx[RPAD_(p)] = ref[p * 3 + 0];
        ry[RPAD_(p)] = ref[p * 3 + 1];
        rz[RPAD_(p)] = ref[p * 3 + 2];
    }
    __syncthreads();

    int wave = threadIdx.x >> 6;
    int lane = threadIdx.x & 63;
    int n = qgroup * 4 + wave;

    const float* qp = xyz + (size_t)((bi * L_ + qi) * N_ + n) * 3;
    float qx = qp[0], qy = qp[1], qz = qp[2];

    int base = lane * 17;               // RPAD_(lane*16)
    unsigned mask = 0;
    #pragma unroll
    for (int j = 0; j < 16; ++j) {
        float dx = qx - rx[base + j];
        float dy = qy - ry[base + j];
        float dz = qz - rz[base + j];
        float d2 = dx * dx + dy * dy;
        d2 = d2 + dz * dz;
        if (d2 < 0.04f) mask |= (1u << j);
    }

    int cnt = __popc(mask);
    int x = cnt;
    #pragma unroll
    for (int off = 1; off < 64; off <<= 1) {
        int y = __shfl_up(x, off, 64);
        if (lane >= off) x += y;
    }
    int pre = x - cnt;                       // exclusive prefix
    int total = __shfl(x, 63, 64);           // total in-radius count

    int r0 = lane * 16;
    int localFirst = mask ? (r0 + __builtin_ctz(mask)) : 0x7fffffff;
    int gfirst = localFirst;
    #pragma unroll
    for (int off = 32; off; off >>= 1) gfirst = min(gfirst, __shfl_xor(gfirst, off, 64));

    int* o = idxt + ((size_t)((qi * B_ + bi) * N_ + n)) * 32 + jf * NS_;

    unsigned m = mask;
    int pos = pre;
    while (m && pos < NS_) {
        int j = __builtin_ctz(m);
        o[pos] = r0 + j;
        m &= m - 1;
        ++pos;
    }
    if (lane == 0) {
        int padv = (total > 0) ? gfirst : 0;
        for (int s = (total < NS_ ? total : NS_); s < NS_; ++s) o[s] = padv;
    }
}

// ---------------------------------------------------------------------------
// K4: attention, relayout. One block (256 thr = 4 waves) per query point.
// Wave w covers heads 2w, 2w+1.
// Phase A (lane = (head-half hh, neighbor j)): in-lane 64-dim QK dot,
//   32-lane-group softmax + attn*disp max.  No per-j wave reductions.
// Phase C (lane = (hh, dim-pair)): PV with dword V loads + spatial proj.
// ---------------------------------------------------------------------------
__global__ __launch_bounds__(256) void attn_kernel(
    const float* __restrict__ xyz, const u16* __restrict__ qkv,
    const int* __restrict__ idxt, const float* __restrict__ wsp,
    u16* __restrict__ fres)
{
    int n = blockIdx.x & 1023;
    int bc = blockIdx.x >> 10;
    int bi = bc & 1;
    int qi = bc >> 1;
    int wave = threadIdx.x >> 6;
    int lane = threadIdx.x & 63;
    int hh = lane >> 5;
    int j = lane & 31;
    int h = wave * 2 + hh;
    int jf = j >> 3;

    int qrow = (bi * L_ + qi) * N_ + n;                  // xyz/qkv row
    int qq = (qi * B_ + bi) * N_ + n;                    // idxt row

    __shared__ float a_s[HEADS_][32];
    __shared__ int grow_s[32];
    __shared__ float da_s[HEADS_][3];

    // --- Phase A: logits ---
    int idx = idxt[(size_t)qq * 32 + j];                 // coalesced 128B / group
    int kr = (bi * L_ + jf) * N_ + idx;

    const u16* kp = qkv + (size_t)kr * 1536 + 512 + h * 64;
    const u16* qp = qkv + (size_t)qrow * 1536 + h * 64;

    bf16x8 kvv[8], qvv[8];
    #pragma unroll
    for (int c = 0; c < 8; ++c) {
        kvv[c] = *(const bf16x8*)(kp + c * 8);
        qvv[c] = *(const bf16x8*)(qp + c * 8);
    }
    float acc = 0.f;
    #pragma unroll
    for (int c = 0; c < 8; ++c)
        #pragma unroll
        for (int e = 0; e < 8; ++e)
            acc += bf2f((u16)kvv[c][e]) * bf2f((u16)qvv[c][e]);

    float lg = acc * 0.125f;                             // scale = dh^-0.5

    // --- softmax over 32-lane group (xor offsets < 32 stay in group) ---
    float mx = lg;
    #pragma unroll
    for (int off = 16; off; off >>= 1) mx = fmaxf(mx, __shfl_xor(mx, off, 64));
    float e = expf(lg - mx);
    float sum = e;
    #pragma unroll
    for (int off = 16; off; off >>= 1) sum += __shfl_xor(sum, off, 64);
    float a = e / sum;
    a_s[h][j] = a;
    if (wave == 0 && hh == 0) grow_s[j] = kr;

    // --- attn * disp max (per head, over 32 neighbors) ---
    float qx = xyz[(size_t)qrow * 3 + 0];
    float qy = xyz[(size_t)qrow * 3 + 1];
    float qz = xyz[(size_t)qrow * 3 + 2];
    float tx = a * (xyz[(size_t)kr * 3 + 0] - qx);
    float ty = a * (xyz[(size_t)kr * 3 + 1] - qy);
    float tz = a * (xyz[(size_t)kr * 3 + 2] - qz);
    #pragma unroll
    for (int off = 16; off; off >>= 1) {
        tx = fmaxf(tx, __shfl_xor(tx, off, 64));
        ty = fmaxf(ty, __shfl_xor(ty, off, 64));
        tz = fmaxf(tz, __shfl_xor(tz, off, 64));
    }
    if (j == 0) { da_s[h][0] = tx; da_s[h][1] = ty; da_s[h][2] = tz; }

    __syncthreads();

    // --- Phase C: PV + spatial projection.  lane -> (hh, dim pair) ---
    int dd = (lane & 31) * 2;                            // dims dd, dd+1
    const u16* vbase = qkv + 1024 + h * 64 + dd;
    float o0 = 0.f, o1 = 0.f;
    #pragma unroll
    for (int t = 0; t < 32; ++t) {
        int krt = grow_s[t];
        float at = a_s[h][t];
        unsigned vv = *(const unsigned*)(vbase + (size_t)krt * 1536);
        o0 += at * bflo(vv);
        o1 += at * bfhi(vv);
    }
    float dax = da_s[h][0], day = da_s[h][1], daz = da_s[h][2];
    float sp0 = dax * wsp[dd]     + day * wsp[64 + dd]     + daz * wsp[128 + dd];
    float sp1 = dax * wsp[dd + 1] + day * wsp[64 + dd + 1] + daz * wsp[128 + dd + 1];

    u16* op = fres + (size_t)qrow * INNER_ + h * 64 + dd;
    unsigned outw = (unsigned)f2bf(o0 + sp0) | ((unsigned)f2bf(o1 + sp1) << 16);
    *(unsigned*)op = outw;
}

// ---------------------------------------------------------------------------
extern "C" void kernel_launch(void* const* d_in, const int* in_sizes, int n_in,
                              void* d_out, int out_size, void* d_ws, size_t ws_size,
                              hipStream_t stream) {
    const float* xyz   = (const float*)d_in[0];   // (2,4,1024,3)
    const float* feat  = (const float*)d_in[1];   // (2,4,1024,512)
    const float* gamma = (const float*)d_in[2];   // (512)
    const float* beta  = (const float*)d_in[3];   // (512)
    const float* wqkv  = (const float*)d_in[4];   // (512,1536)
    const float* wsp   = (const float*)d_in[5];   // (3,64)
    const float* wout  = (const float*)d_in[6];   // (512,512)
    const float* bout  = (const float*)d_in[7];   // (512)
    float* out = (float*)d_out;

    char* ws = (char*)d_ws;
    u16* normf = (u16*)ws;                 ws += (size_t)ROWS_ * DIM_ * 2;        // 8 MB
    u16* wqkvT = (u16*)ws;                 ws += (size_t)3 * INNER_ * DIM_ * 2;   // 1.5 MB
    u16* woutT = (u16*)ws;                 ws += (size_t)DIM_ * INNER_ * 2;       // 0.5 MB
    u16* qkv   = (u16*)ws;                 ws += (size_t)ROWS_ * 3 * INNER_ * 2;  // 24 MB
    int* idxt  = (int*)ws;                 ws += (size_t)L_ * NFR_ * N_ * NS_ * 4;// 1 MB
    u16* fres  = normf;   // alias: normf is dead after GEMM1 completes

    transpose_w<<<4096, 256, 0, stream>>>(wqkv, wout, wqkvT, woutT);
    ln_kernel<<<ROWS_, 256, 0, stream>>>(feat, gamma, beta, normf);
    // qkv = normf @ w_qkv : M=8192, N=1536, K=512
    gemm_bt<<<64 * 12, 256, 0, stream>>>(normf, wqkvT, qkv, nullptr,
                                         ROWS_, 3 * INNER_, DIM_, 12, 0, nullptr, nullptr);
    ballq_kernel<<<32 * 256, 256, 0, stream>>>(xyz, idxt);
    attn_kernel<<<L_ * B_ * N_, 256, 0, stream>>>(xyz, qkv, idxt, wsp, fres);
    // out = gelu(fres @ w_out + b_out) + feature : M=8192, N=512, K=512
    gemm_bt<<<64 * 4, 256, 0, stream>>>(fres, woutT, nullptr, out,
                                        ROWS_, DIM_, INNER_, 4, 1, bout, feat);
}